// Round 6
// baseline (237.489 us; speedup 1.0000x reference)
//
#include <hip/hip_runtime.h>

// VectorQuantizer: x[128,512,64] f32, codebook[1024,64] f32
// outputs (flat in d_out, float32): quantized[4194304], loss[1], indices[65536]
//
// R6: kMF = MFMA screen (split-bf16, K=192), 32 rows/block (2 row-tiles),
// grid 2048 -> 8 blocks/CU, __launch_bounds__(256,6) -> 6 waves/SIMD for
// latency hiding (R5 was 4 waves/SIMD and latency-bound: busy-sum 39%).
// unroll-2 code-tile loop lets the scheduler hoist next-tile B loads.
// k4: barrier-free wave-shuffle f64 reduce (was 8-barrier LDS tree).
// Exactness: fp32 top-2 gap screen, TAU-flagged rows get fp32-exact sweep +
// selective fp64 (k3) -> argmin fp64-exact. Loss fp64, fixed order.

typedef __attribute__((ext_vector_type(8))) short bf16x8;
typedef __attribute__((ext_vector_type(4))) float f32x4;
typedef __attribute__((ext_vector_type(8))) unsigned short u16x8;

static constexpr int Vn    = 1024;
static constexpr int Hn    = 64;
static constexpr int Nrows = 128 * 512;          // 65536
static constexpr int QSZ   = Nrows * Hn;         // 4194304
#define TAU 0.05f
#define MARGIN 4e-3f

__device__ inline unsigned short f2bf(float f) {         // RNE fp32->bf16
  unsigned u = __float_as_uint(f);
  return (unsigned short)((u + 0x7fffu + ((u >> 16) & 1u)) >> 16);
}
__device__ inline float bf2f(unsigned short h) {
  return __uint_as_float(((unsigned)h) << 16);
}

// ---- ws layout (bytes) ----
// 0      : double cnormd[1024]       (8192)
// 8192   : double partials[1024]     (8192; region reserves 32768)
// 40960  : float  cnormf[1024]       (4096)
// 45056  : int    bestIdx[65536]     (262144)
// 307200 : int    flagCount          (8)
// 307208 : int    flagList[65536]    (262144)
// 573440 : ushort cw[1024*128]       (262144)   [ch(64)|cl(64)] per code

// Codebook prep: fp64 norms + bf16 hi/lo split.
__global__ __launch_bounds__(256) void kC(
    const float* __restrict__ cb, unsigned short* __restrict__ cw,
    double* __restrict__ cnd, float* __restrict__ cnf,
    int* __restrict__ flagCount) {
  int v = blockIdx.x * 256 + threadIdx.x;
  if (v == 0) *flagCount = 0;
  if (v >= Vn) return;
  const float* c = cb + v * Hn;
  double s = 0;
  unsigned short hs[64], ls[64];
  for (int k = 0; k < 64; ++k) {
    float f = c[k];
    s += (double)f * (double)f;
    unsigned short h = f2bf(f);
    hs[k] = h;
    ls[k] = f2bf(f - bf2f(h));
  }
  cnd[v] = s;
  cnf[v] = (float)s;
  u16x8* dst = (u16x8*)(cw + v * 128);
#pragma unroll
  for (int k = 0; k < 8; ++k) {
    u16x8 a; for (int j = 0; j < 8; ++j) a[j] = hs[k * 8 + j];
    dst[k] = a;
  }
#pragma unroll
  for (int k = 0; k < 8; ++k) {
    u16x8 a; for (int j = 0; j < 8; ++j) a[j] = ls[k * 8 + j];
    dst[8 + k] = a;
  }
}

// Fused MFMA screen + argmin. Block = 4 waves, 32 rows (2 row-tiles); wave w
// sweeps codes [256w, 256w+256) as 16 code-tiles. Per 16x16 tile: K=192 via
// 6 MFMA (xh.ch + xh.cl + xl.ch), 2 independent acc chains.
// C frag: col=lane&15, row=4*(lane>>4)+reg (m89-verified; validated R4/R5).
__global__ __launch_bounds__(256, 6) void kMF(
    const float* __restrict__ x, const unsigned short* __restrict__ cw,
    const float* __restrict__ cnf, int* __restrict__ bestIdx,
    int* __restrict__ flagCount, int* __restrict__ flagList,
    float* __restrict__ outIdx) {
  __shared__ float sB1[4][32], sB2[4][32];
  __shared__ int   sI[4][32];
  const int tid = threadIdx.x;
  const int lane = tid & 63;
  const int w = tid >> 6;
  const int l15 = lane & 15, g = lane >> 4;
  const int rowBase = blockIdx.x * 32;

  // A fragments: 2 row-tiles x {xh0,xh1,xl0,xl1}, converted from f32 here.
  bf16x8 A[2][4];
#pragma unroll
  for (int rt = 0; rt < 2; ++rt) {
    const float* xr = x + (long)(rowBase + rt * 16 + l15) * Hn + g * 8;
    float4 fa0 = *(const float4*)(xr + 0);
    float4 fa1 = *(const float4*)(xr + 4);
    float4 fb0 = *(const float4*)(xr + 32);
    float4 fb1 = *(const float4*)(xr + 36);
    float va[8] = {fa0.x, fa0.y, fa0.z, fa0.w, fa1.x, fa1.y, fa1.z, fa1.w};
    float vb[8] = {fb0.x, fb0.y, fb0.z, fb0.w, fb1.x, fb1.y, fb1.z, fb1.w};
    bf16x8 h0, h1, l0, l1;
#pragma unroll
    for (int j = 0; j < 8; ++j) {
      unsigned short h = f2bf(va[j]);
      h0[j] = (short)h;
      l0[j] = (short)f2bf(va[j] - bf2f(h));
      unsigned short h2 = f2bf(vb[j]);
      h1[j] = (short)h2;
      l1[j] = (short)f2bf(vb[j] - bf2f(h2));
    }
    A[rt][0] = h0; A[rt][1] = h1; A[rt][2] = l0; A[rt][3] = l1;
  }

  float b1[2][4], b2[2][4];
  int   bi[2][4];
#pragma unroll
  for (int rt = 0; rt < 2; ++rt)
#pragma unroll
    for (int r = 0; r < 4; ++r) { b1[rt][r] = 3.4e38f; b2[rt][r] = 3.4e38f; bi[rt][r] = 0; }

  const int codeBase = w * 256;
#pragma unroll 2
  for (int ct = 0; ct < 16; ++ct) {
    const int c0 = codeBase + ct * 16;
    const unsigned short* br = cw + (long)(c0 + l15) * 128 + g * 8;
    bf16x8 Bh0 = *(const bf16x8*)(br + 0);
    bf16x8 Bh1 = *(const bf16x8*)(br + 32);
    bf16x8 Bl0 = *(const bf16x8*)(br + 64);
    bf16x8 Bl1 = *(const bf16x8*)(br + 96);
    const float cnfv = cnf[c0 + l15];
    const int v = c0 + l15;
#pragma unroll
    for (int rt = 0; rt < 2; ++rt) {
      f32x4 acc = {0.f, 0.f, 0.f, 0.f};
      acc = __builtin_amdgcn_mfma_f32_16x16x32_bf16(A[rt][0], Bh0, acc, 0, 0, 0); // xh.ch
      acc = __builtin_amdgcn_mfma_f32_16x16x32_bf16(A[rt][1], Bh1, acc, 0, 0, 0);
      acc = __builtin_amdgcn_mfma_f32_16x16x32_bf16(A[rt][0], Bl0, acc, 0, 0, 0); // xh.cl
      acc = __builtin_amdgcn_mfma_f32_16x16x32_bf16(A[rt][1], Bl1, acc, 0, 0, 0);
      acc = __builtin_amdgcn_mfma_f32_16x16x32_bf16(A[rt][2], Bh0, acc, 0, 0, 0); // xl.ch
      acc = __builtin_amdgcn_mfma_f32_16x16x32_bf16(A[rt][3], Bh1, acc, 0, 0, 0);
#pragma unroll
      for (int r = 0; r < 4; ++r) {
        float key = fmaf(-2.0f, acc[r], cnfv);
        bool lt = key < b1[rt][r];
        b2[rt][r] = __builtin_amdgcn_fmed3f(key, b1[rt][r], b2[rt][r]); // 2nd-best
        b1[rt][r] = fminf(b1[rt][r], key);
        bi[rt][r] = lt ? v : bi[rt][r];
      }
    }
  }

  // Merge top-2 across the 16 lanes holding each row (cols 0..15 subsets).
#pragma unroll
  for (int rt = 0; rt < 2; ++rt)
#pragma unroll
    for (int r = 0; r < 4; ++r) {
      float B1r = b1[rt][r], B2r = b2[rt][r];
      int Ir = bi[rt][r];
#pragma unroll
      for (int m = 1; m < 16; m <<= 1) {
        float o1 = __shfl_xor(B1r, m), o2 = __shfl_xor(B2r, m);
        int oi = __shfl_xor(Ir, m);
        float worse = fmaxf(B1r, o1);
        B2r = fminf(fminf(B2r, o2), worse);
        bool take = (o1 < B1r) || (o1 == B1r && oi < Ir);
        B1r = take ? o1 : B1r;
        Ir  = take ? oi : Ir;
      }
      b1[rt][r] = B1r; b2[rt][r] = B2r; bi[rt][r] = Ir;
    }

  // Writers: lane with l15==r publishes row rt*16 + 4g + r (static reg idx).
#pragma unroll
  for (int rt = 0; rt < 2; ++rt)
#pragma unroll
    for (int r = 0; r < 4; ++r)
      if (l15 == r) {
        int rowIn = rt * 16 + 4 * g + r;
        sB1[w][rowIn] = b1[rt][r];
        sB2[w][rowIn] = b2[rt][r];
        sI[w][rowIn]  = bi[rt][r];
      }
  __syncthreads();

  if (tid < 32) {
    float B1 = sB1[0][tid], B2 = sB2[0][tid];
    int I = sI[0][tid];
#pragma unroll
    for (int ww = 1; ww < 4; ++ww) {
      float o1 = sB1[ww][tid], o2 = sB2[ww][tid];
      int oi = sI[ww][tid];
      float worse = fmaxf(B1, o1);
      B2 = fminf(fminf(B2, o2), worse);
      bool take = (o1 < B1) || (o1 == B1 && oi < I);
      B1 = take ? o1 : B1;
      I  = take ? oi : I;
    }
    const int row = rowBase + tid;
    bestIdx[row] = I;
    outIdx[row] = (float)I;
    if (B2 - B1 <= TAU) {
      int slot = atomicAdd(flagCount, 1);
      flagList[slot] = row;                      // order-independent use
    }
  }
}

// Recheck flagged rows: exact-fp32 sweep of all 1024 codes, then fp64 keys
// only for codes within MARGIN of the fp32 min (|key32-key64| <= ~5e-4).
__global__ __launch_bounds__(256) void k3_recheck(
    const float* __restrict__ x, const float* __restrict__ cb,
    const double* __restrict__ cnd, const float* __restrict__ cnf,
    int* __restrict__ bestIdx,
    const int* __restrict__ flagCount, const int* __restrict__ flagList,
    float* __restrict__ outIdx) {
  __shared__ float xs[64];
  __shared__ float rmin[256];
  __shared__ double dk[256];
  __shared__ int    di[256];
  const int tid = threadIdx.x;
  const int cnt = *flagCount;

  for (int jj = blockIdx.x; jj < cnt; jj += gridDim.x) {
    const int row = flagList[jj];
    if (tid < 16)
      reinterpret_cast<float4*>(xs)[tid] =
          reinterpret_cast<const float4*>(x + (long)row * Hn)[tid];
    __syncthreads();

    float key32[4];
#pragma unroll
    for (int cc = 0; cc < 4; ++cc) {
      const int v = cc * 256 + tid;
      const float4* c4 = reinterpret_cast<const float4*>(cb + v * Hn);
      float d0 = 0, d1 = 0, d2 = 0, d3 = 0;
#pragma unroll
      for (int k = 0; k < 16; ++k) {
        float4 f = c4[k];
        d0 = fmaf(f.x, xs[4 * k + 0], d0);
        d1 = fmaf(f.y, xs[4 * k + 1], d1);
        d2 = fmaf(f.z, xs[4 * k + 2], d2);
        d3 = fmaf(f.w, xs[4 * k + 3], d3);
      }
      key32[cc] = cnf[v] - 2.0f * ((d0 + d1) + (d2 + d3));
    }

    float m = fminf(fminf(key32[0], key32[1]), fminf(key32[2], key32[3]));
    rmin[tid] = m;
    __syncthreads();
    for (int s = 128; s > 0; s >>= 1) {
      if (tid < s) rmin[tid] = fminf(rmin[tid], rmin[tid + s]);
      __syncthreads();
    }
    const float m1 = rmin[0];

    double bk = 1e300;
    int bidx = 0x7FFFFFFF;
#pragma unroll
    for (int cc = 0; cc < 4; ++cc) {
      if (key32[cc] <= m1 + MARGIN) {
        const int v = cc * 256 + tid;
        const float4* c4 = reinterpret_cast<const float4*>(cb + v * Hn);
        double a0 = 0, a1 = 0, a2 = 0, a3 = 0;
#pragma unroll
        for (int k = 0; k < 16; ++k) {
          float4 f = c4[k];
          a0 += (double)f.x * (double)xs[4 * k + 0];
          a1 += (double)f.y * (double)xs[4 * k + 1];
          a2 += (double)f.z * (double)xs[4 * k + 2];
          a3 += (double)f.w * (double)xs[4 * k + 3];
        }
        double key = cnd[v] - 2.0 * ((a0 + a1) + (a2 + a3));
        if (key < bk || (key == bk && v < bidx)) { bk = key; bidx = v; }
      }
    }
    dk[tid] = bk; di[tid] = bidx;
    __syncthreads();
    for (int s = 128; s > 0; s >>= 1) {
      if (tid < s) {
        if (dk[tid + s] < dk[tid] ||
            (dk[tid + s] == dk[tid] && di[tid + s] < di[tid])) {
          dk[tid] = dk[tid + s]; di[tid] = di[tid + s];
        }
      }
      __syncthreads();
    }
    if (tid == 0) {
      bestIdx[row] = di[0];
      outIdx[row] = (float)di[0];
    }
    __syncthreads();
  }
}

// Gather quantized + fp64 loss partials (wave-shuffle reduce, barrier-light).
__global__ __launch_bounds__(256) void k4_gather(
    const float* __restrict__ x, const float* __restrict__ cb,
    const int* __restrict__ bestIdx, float* __restrict__ out,
    double* __restrict__ partials) {
  __shared__ double wsum[4];
  const int tid = threadIdx.x;
  double acc = 0;
#pragma unroll
  for (int q = 0; q < 4; ++q) {
    const int t = blockIdx.x * 1024 + q * 256 + tid;   // float4 index
    const int i = t * 4;
    const int row = i >> 6;
    const int h4 = (i & 63) >> 2;
    const int idx = bestIdx[row];
    float4 qv = reinterpret_cast<const float4*>(cb)[idx * 16 + h4];
    float4 xv = reinterpret_cast<const float4*>(x)[t];
    reinterpret_cast<float4*>(out)[t] = qv;
    double dx = (double)qv.x - (double)xv.x;
    double dy = (double)qv.y - (double)xv.y;
    double dz = (double)qv.z - (double)xv.z;
    double dw = (double)qv.w - (double)xv.w;
    acc += dx * dx + dy * dy + dz * dz + dw * dw;
  }
#pragma unroll
  for (int m = 32; m > 0; m >>= 1) acc += __shfl_down(acc, m);  // fixed order
  if ((tid & 63) == 0) wsum[tid >> 6] = acc;
  __syncthreads();
  if (tid == 0) partials[blockIdx.x] = (wsum[0] + wsum[1]) + (wsum[2] + wsum[3]);
}

__global__ __launch_bounds__(256) void k6_loss(const double* __restrict__ partials,
                                               float* __restrict__ out) {
  __shared__ double red[256];
  double a = 0;
  for (int k = threadIdx.x; k < 1024; k += 256) a += partials[k];  // fixed order
  red[threadIdx.x] = a;
  __syncthreads();
  for (int s = 128; s > 0; s >>= 1) {
    if (threadIdx.x < s) red[threadIdx.x] += red[threadIdx.x + s];
    __syncthreads();
  }
  if (threadIdx.x == 0)
    out[QSZ] = (float)(1.25 * red[0] / (double)QSZ);
}

extern "C" void kernel_launch(void* const* d_in, const int* in_sizes, int n_in,
                              void* d_out, int out_size, void* d_ws, size_t ws_size,
                              hipStream_t stream) {
  const float* x  = (const float*)d_in[0];
  const float* cb = (const float*)d_in[1];
  float* out = (float*)d_out;
  char* ws = (char*)d_ws;

  double* cnd      = (double*)(ws + 0);
  double* partials = (double*)(ws + 8192);
  float*  cnf      = (float*) (ws + 40960);
  int*    bestIdx  = (int*)   (ws + 45056);
  int*    flagCnt  = (int*)   (ws + 307200);
  int*    flagList = (int*)   (ws + 307208);
  unsigned short* cw = (unsigned short*)(ws + 573440);

  float* outIdx = out + QSZ + 1;

  kC        <<<4,    256, 0, stream>>>(cb, cw, cnd, cnf, flagCnt);
  kMF       <<<2048, 256, 0, stream>>>(x, cw, cnf, bestIdx, flagCnt, flagList, outIdx);
  k3_recheck<<<1024, 256, 0, stream>>>(x, cb, cnd, cnf, bestIdx, flagCnt, flagList, outIdx);
  k4_gather <<<1024, 256, 0, stream>>>(x, cb, bestIdx, out, partials);
  k6_loss   <<<1,    256, 0, stream>>>(partials, out);
}

// Round 7
// 172.138 us; speedup vs baseline: 1.3796x; 1.3796x over previous
//
#include <hip/hip_runtime.h>

// VectorQuantizer: x[128,512,64] f32, codebook[1024,64] f32
// outputs (flat in d_out, float32): quantized[4194304], loss[1], indices[65536]
//
// R7: R6 structure minus the spill bomb. kMF = MFMA screen (split-bf16,
// K=192), 32 rows/block (2 row-tiles), grid 2048, __launch_bounds__(256,4)
// (R6's (256,6) forced VGPR=40 + 137MB scratch writes -> 2x regression).
// New: A-frags carry -2x (folded scale) and MFMA C-init carries ||c||^2,
// so key = acc[r] directly -> epilogue 5->4 VALU ops, no dependent fmaf.
// Exactness: fp32 top-2 gap screen (screen err <= ~2.4e-2 < TAU=0.05);
// flagged rows -> k3 fp32-exact sweep + selective fp64 -> argmin fp64-exact.
// Loss fp64, fixed order (deterministic).

typedef __attribute__((ext_vector_type(8))) short bf16x8;
typedef __attribute__((ext_vector_type(4))) float f32x4;
typedef __attribute__((ext_vector_type(8))) unsigned short u16x8;

static constexpr int Vn    = 1024;
static constexpr int Hn    = 64;
static constexpr int Nrows = 128 * 512;          // 65536
static constexpr int QSZ   = Nrows * Hn;         // 4194304
#define TAU 0.05f
#define MARGIN 4e-3f

__device__ inline unsigned short f2bf(float f) {         // RNE fp32->bf16
  unsigned u = __float_as_uint(f);
  return (unsigned short)((u + 0x7fffu + ((u >> 16) & 1u)) >> 16);
}
__device__ inline float bf2f(unsigned short h) {
  return __uint_as_float(((unsigned)h) << 16);
}

// ---- ws layout (bytes) ----
// 0      : double cnormd[1024]       (8192)
// 8192   : double partials[1024]     (8192; region reserves 32768)
// 40960  : float  cnormf[1024]       (4096)
// 45056  : int    bestIdx[65536]     (262144)
// 307200 : int    flagCount          (8)
// 307208 : int    flagList[65536]    (262144)
// 573440 : ushort cw[1024*128]       (262144)   [ch(64)|cl(64)] per code

// Codebook prep: fp64 norms + bf16 hi/lo split.
__global__ __launch_bounds__(256) void kC(
    const float* __restrict__ cb, unsigned short* __restrict__ cw,
    double* __restrict__ cnd, float* __restrict__ cnf,
    int* __restrict__ flagCount) {
  int v = blockIdx.x * 256 + threadIdx.x;
  if (v == 0) *flagCount = 0;
  if (v >= Vn) return;
  const float* c = cb + v * Hn;
  double s = 0;
  unsigned short hs[64], ls[64];
  for (int k = 0; k < 64; ++k) {
    float f = c[k];
    s += (double)f * (double)f;
    unsigned short h = f2bf(f);
    hs[k] = h;
    ls[k] = f2bf(f - bf2f(h));
  }
  cnd[v] = s;
  cnf[v] = (float)s;
  u16x8* dst = (u16x8*)(cw + v * 128);
#pragma unroll
  for (int k = 0; k < 8; ++k) {
    u16x8 a; for (int j = 0; j < 8; ++j) a[j] = hs[k * 8 + j];
    dst[k] = a;
  }
#pragma unroll
  for (int k = 0; k < 8; ++k) {
    u16x8 a; for (int j = 0; j < 8; ++j) a[j] = ls[k * 8 + j];
    dst[8 + k] = a;
  }
}

// Fused MFMA screen + argmin. Block = 4 waves, 32 rows (2 row-tiles); wave w
// sweeps codes [256w, 256w+256) as 16 code-tiles. Per 16x16 tile: K=192 via
// 6 MFMA ((-2xh).ch + (-2xh).cl + (-2xl).ch), C-init = ||c||^2 -> acc = key.
// C frag: col=lane&15, row=4*(lane>>4)+reg (m89-verified; validated R4-R6).
__global__ __launch_bounds__(256, 4) void kMF(
    const float* __restrict__ x, const unsigned short* __restrict__ cw,
    const float* __restrict__ cnf, int* __restrict__ bestIdx,
    int* __restrict__ flagCount, int* __restrict__ flagList,
    float* __restrict__ outIdx) {
  __shared__ float sB1[4][32], sB2[4][32];
  __shared__ int   sI[4][32];
  const int tid = threadIdx.x;
  const int lane = tid & 63;
  const int w = tid >> 6;
  const int l15 = lane & 15, g = lane >> 4;
  const int rowBase = blockIdx.x * 32;

  // A fragments: 2 row-tiles x {h0,h1,l0,l1} of (-2x), converted here.
  bf16x8 A[2][4];
#pragma unroll
  for (int rt = 0; rt < 2; ++rt) {
    const float* xr = x + (long)(rowBase + rt * 16 + l15) * Hn + g * 8;
    float4 fa0 = *(const float4*)(xr + 0);
    float4 fa1 = *(const float4*)(xr + 4);
    float4 fb0 = *(const float4*)(xr + 32);
    float4 fb1 = *(const float4*)(xr + 36);
    float va[8] = {fa0.x, fa0.y, fa0.z, fa0.w, fa1.x, fa1.y, fa1.z, fa1.w};
    float vb[8] = {fb0.x, fb0.y, fb0.z, fb0.w, fb1.x, fb1.y, fb1.z, fb1.w};
    bf16x8 h0, h1, l0, l1;
#pragma unroll
    for (int j = 0; j < 8; ++j) {
      float sa = -2.0f * va[j];
      unsigned short h = f2bf(sa);
      h0[j] = (short)h;
      l0[j] = (short)f2bf(sa - bf2f(h));
      float sb = -2.0f * vb[j];
      unsigned short h2 = f2bf(sb);
      h1[j] = (short)h2;
      l1[j] = (short)f2bf(sb - bf2f(h2));
    }
    A[rt][0] = h0; A[rt][1] = h1; A[rt][2] = l0; A[rt][3] = l1;
  }

  float b1[2][4], b2[2][4];
  int   bi[2][4];
#pragma unroll
  for (int rt = 0; rt < 2; ++rt)
#pragma unroll
    for (int r = 0; r < 4; ++r) { b1[rt][r] = 3.4e38f; b2[rt][r] = 3.4e38f; bi[rt][r] = 0; }

  const int codeBase = w * 256;
#pragma unroll 2
  for (int ct = 0; ct < 16; ++ct) {
    const int c0 = codeBase + ct * 16;
    const unsigned short* br = cw + (long)(c0 + l15) * 128 + g * 8;
    bf16x8 Bh0 = *(const bf16x8*)(br + 0);
    bf16x8 Bh1 = *(const bf16x8*)(br + 32);
    bf16x8 Bl0 = *(const bf16x8*)(br + 64);
    bf16x8 Bl1 = *(const bf16x8*)(br + 96);
    const float cnfv = cnf[c0 + l15];
    const int v = c0 + l15;
#pragma unroll
    for (int rt = 0; rt < 2; ++rt) {
      f32x4 acc = {cnfv, cnfv, cnfv, cnfv};      // C-init = ||c||^2
      acc = __builtin_amdgcn_mfma_f32_16x16x32_bf16(A[rt][0], Bh0, acc, 0, 0, 0);
      acc = __builtin_amdgcn_mfma_f32_16x16x32_bf16(A[rt][1], Bh1, acc, 0, 0, 0);
      acc = __builtin_amdgcn_mfma_f32_16x16x32_bf16(A[rt][0], Bl0, acc, 0, 0, 0);
      acc = __builtin_amdgcn_mfma_f32_16x16x32_bf16(A[rt][1], Bl1, acc, 0, 0, 0);
      acc = __builtin_amdgcn_mfma_f32_16x16x32_bf16(A[rt][2], Bh0, acc, 0, 0, 0);
      acc = __builtin_amdgcn_mfma_f32_16x16x32_bf16(A[rt][3], Bh1, acc, 0, 0, 0);
#pragma unroll
      for (int r = 0; r < 4; ++r) {
        float key = acc[r];                      // = ||c||^2 - 2 x.c
        bool lt = key < b1[rt][r];
        b2[rt][r] = __builtin_amdgcn_fmed3f(key, b1[rt][r], b2[rt][r]); // 2nd-best
        b1[rt][r] = fminf(b1[rt][r], key);
        bi[rt][r] = lt ? v : bi[rt][r];
      }
    }
  }

  // Merge top-2 across the 16 lanes holding each row (cols 0..15 subsets).
#pragma unroll
  for (int rt = 0; rt < 2; ++rt)
#pragma unroll
    for (int r = 0; r < 4; ++r) {
      float B1r = b1[rt][r], B2r = b2[rt][r];
      int Ir = bi[rt][r];
#pragma unroll
      for (int m = 1; m < 16; m <<= 1) {
        float o1 = __shfl_xor(B1r, m), o2 = __shfl_xor(B2r, m);
        int oi = __shfl_xor(Ir, m);
        float worse = fmaxf(B1r, o1);
        B2r = fminf(fminf(B2r, o2), worse);
        bool take = (o1 < B1r) || (o1 == B1r && oi < Ir);
        B1r = take ? o1 : B1r;
        Ir  = take ? oi : Ir;
      }
      b1[rt][r] = B1r; b2[rt][r] = B2r; bi[rt][r] = Ir;
    }

  // Writers: lane with l15==r publishes row rt*16 + 4g + r (static reg idx).
#pragma unroll
  for (int rt = 0; rt < 2; ++rt)
#pragma unroll
    for (int r = 0; r < 4; ++r)
      if (l15 == r) {
        int rowIn = rt * 16 + 4 * g + r;
        sB1[w][rowIn] = b1[rt][r];
        sB2[w][rowIn] = b2[rt][r];
        sI[w][rowIn]  = bi[rt][r];
      }
  __syncthreads();

  if (tid < 32) {
    float B1 = sB1[0][tid], B2 = sB2[0][tid];
    int I = sI[0][tid];
#pragma unroll
    for (int ww = 1; ww < 4; ++ww) {
      float o1 = sB1[ww][tid], o2 = sB2[ww][tid];
      int oi = sI[ww][tid];
      float worse = fmaxf(B1, o1);
      B2 = fminf(fminf(B2, o2), worse);
      bool take = (o1 < B1) || (o1 == B1 && oi < I);
      B1 = take ? o1 : B1;
      I  = take ? oi : I;
    }
    const int row = rowBase + tid;
    bestIdx[row] = I;
    outIdx[row] = (float)I;
    if (B2 - B1 <= TAU) {
      int slot = atomicAdd(flagCount, 1);
      flagList[slot] = row;                      // order-independent use
    }
  }
}

// Recheck flagged rows: exact-fp32 sweep of all 1024 codes, then fp64 keys
// only for codes within MARGIN of the fp32 min (|key32-key64| <= ~5e-4).
__global__ __launch_bounds__(256) void k3_recheck(
    const float* __restrict__ x, const float* __restrict__ cb,
    const double* __restrict__ cnd, const float* __restrict__ cnf,
    int* __restrict__ bestIdx,
    const int* __restrict__ flagCount, const int* __restrict__ flagList,
    float* __restrict__ outIdx) {
  __shared__ float xs[64];
  __shared__ float rmin[256];
  __shared__ double dk[256];
  __shared__ int    di[256];
  const int tid = threadIdx.x;
  const int cnt = *flagCount;

  for (int jj = blockIdx.x; jj < cnt; jj += gridDim.x) {
    const int row = flagList[jj];
    if (tid < 16)
      reinterpret_cast<float4*>(xs)[tid] =
          reinterpret_cast<const float4*>(x + (long)row * Hn)[tid];
    __syncthreads();

    float key32[4];
#pragma unroll
    for (int cc = 0; cc < 4; ++cc) {
      const int v = cc * 256 + tid;
      const float4* c4 = reinterpret_cast<const float4*>(cb + v * Hn);
      float d0 = 0, d1 = 0, d2 = 0, d3 = 0;
#pragma unroll
      for (int k = 0; k < 16; ++k) {
        float4 f = c4[k];
        d0 = fmaf(f.x, xs[4 * k + 0], d0);
        d1 = fmaf(f.y, xs[4 * k + 1], d1);
        d2 = fmaf(f.z, xs[4 * k + 2], d2);
        d3 = fmaf(f.w, xs[4 * k + 3], d3);
      }
      key32[cc] = cnf[v] - 2.0f * ((d0 + d1) + (d2 + d3));
    }

    float m = fminf(fminf(key32[0], key32[1]), fminf(key32[2], key32[3]));
    rmin[tid] = m;
    __syncthreads();
    for (int s = 128; s > 0; s >>= 1) {
      if (tid < s) rmin[tid] = fminf(rmin[tid], rmin[tid + s]);
      __syncthreads();
    }
    const float m1 = rmin[0];

    double bk = 1e300;
    int bidx = 0x7FFFFFFF;
#pragma unroll
    for (int cc = 0; cc < 4; ++cc) {
      if (key32[cc] <= m1 + MARGIN) {
        const int v = cc * 256 + tid;
        const float4* c4 = reinterpret_cast<const float4*>(cb + v * Hn);
        double a0 = 0, a1 = 0, a2 = 0, a3 = 0;
#pragma unroll
        for (int k = 0; k < 16; ++k) {
          float4 f = c4[k];
          a0 += (double)f.x * (double)xs[4 * k + 0];
          a1 += (double)f.y * (double)xs[4 * k + 1];
          a2 += (double)f.z * (double)xs[4 * k + 2];
          a3 += (double)f.w * (double)xs[4 * k + 3];
        }
        double key = cnd[v] - 2.0 * ((a0 + a1) + (a2 + a3));
        if (key < bk || (key == bk && v < bidx)) { bk = key; bidx = v; }
      }
    }
    dk[tid] = bk; di[tid] = bidx;
    __syncthreads();
    for (int s = 128; s > 0; s >>= 1) {
      if (tid < s) {
        if (dk[tid + s] < dk[tid] ||
            (dk[tid + s] == dk[tid] && di[tid + s] < di[tid])) {
          dk[tid] = dk[tid + s]; di[tid] = di[tid + s];
        }
      }
      __syncthreads();
    }
    if (tid == 0) {
      bestIdx[row] = di[0];
      outIdx[row] = (float)di[0];
    }
    __syncthreads();
  }
}

// Gather quantized + fp64 loss partials (wave-shuffle reduce, barrier-light).
__global__ __launch_bounds__(256) void k4_gather(
    const float* __restrict__ x, const float* __restrict__ cb,
    const int* __restrict__ bestIdx, float* __restrict__ out,
    double* __restrict__ partials) {
  __shared__ double wsum[4];
  const int tid = threadIdx.x;
  double acc = 0;
#pragma unroll
  for (int q = 0; q < 4; ++q) {
    const int t = blockIdx.x * 1024 + q * 256 + tid;   // float4 index
    const int i = t * 4;
    const int row = i >> 6;
    const int h4 = (i & 63) >> 2;
    const int idx = bestIdx[row];
    float4 qv = reinterpret_cast<const float4*>(cb)[idx * 16 + h4];
    float4 xv = reinterpret_cast<const float4*>(x)[t];
    reinterpret_cast<float4*>(out)[t] = qv;
    double dx = (double)qv.x - (double)xv.x;
    double dy = (double)qv.y - (double)xv.y;
    double dz = (double)qv.z - (double)xv.z;
    double dw = (double)qv.w - (double)xv.w;
    acc += dx * dx + dy * dy + dz * dz + dw * dw;
  }
#pragma unroll
  for (int m = 32; m > 0; m >>= 1) acc += __shfl_down(acc, m);  // fixed order
  if ((tid & 63) == 0) wsum[tid >> 6] = acc;
  __syncthreads();
  if (tid == 0) partials[blockIdx.x] = (wsum[0] + wsum[1]) + (wsum[2] + wsum[3]);
}

__global__ __launch_bounds__(256) void k6_loss(const double* __restrict__ partials,
                                               float* __restrict__ out) {
  __shared__ double red[256];
  double a = 0;
  for (int k = threadIdx.x; k < 1024; k += 256) a += partials[k];  // fixed order
  red[threadIdx.x] = a;
  __syncthreads();
  for (int s = 128; s > 0; s >>= 1) {
    if (threadIdx.x < s) red[threadIdx.x] += red[threadIdx.x + s];
    __syncthreads();
  }
  if (threadIdx.x == 0)
    out[QSZ] = (float)(1.25 * red[0] / (double)QSZ);
}

extern "C" void kernel_launch(void* const* d_in, const int* in_sizes, int n_in,
                              void* d_out, int out_size, void* d_ws, size_t ws_size,
                              hipStream_t stream) {
  const float* x  = (const float*)d_in[0];
  const float* cb = (const float*)d_in[1];
  float* out = (float*)d_out;
  char* ws = (char*)d_ws;

  double* cnd      = (double*)(ws + 0);
  double* partials = (double*)(ws + 8192);
  float*  cnf      = (float*) (ws + 40960);
  int*    bestIdx  = (int*)   (ws + 45056);
  int*    flagCnt  = (int*)   (ws + 307200);
  int*    flagList = (int*)   (ws + 307208);
  unsigned short* cw = (unsigned short*)(ws + 573440);

  float* outIdx = out + QSZ + 1;

  kC        <<<4,    256, 0, stream>>>(cb, cw, cnd, cnf, flagCnt);
  kMF       <<<2048, 256, 0, stream>>>(x, cw, cnf, bestIdx, flagCnt, flagList, outIdx);
  k3_recheck<<<1024, 256, 0, stream>>>(x, cb, cnd, cnf, bestIdx, flagCnt, flagList, outIdx);
  k4_gather <<<1024, 256, 0, stream>>>(x, cb, bestIdx, out, partials);
  k6_loss   <<<1,    256, 0, stream>>>(partials, out);
}

// Round 8
// 138.068 us; speedup vs baseline: 1.7201x; 1.2468x over previous
//
#include <hip/hip_runtime.h>

// VectorQuantizer: x[128,512,64] f32, codebook[1024,64] f32
// outputs (flat in d_out, float32): quantized[4194304], loss[1], indices[65536]
//
// R8: kMF with explicit register double-buffered B + prefetched cnf.
// R5/R7 showed the compiler minimizes VGPRs (60) leaving ~no registers for
// outstanding loads -> per-tile L2 latency serialization (79us, occupancy-
// insensitive). Full unroll + 2-deep B buffer + cnfv[16] prologue prefetch
// (all static indices) forces load-ahead; __launch_bounds__(256,3) gives the
// allocator ~170 regs of headroom (R6 lesson: never starve the allocator).
// kC rewritten: 4096 threads, coalesced float4, 4-lane shfl fp64 reduce.
// Exactness: fp32 top-2 gap screen (err <= ~2.4e-2 < TAU=0.05); flagged rows
// -> k3 fp32-exact sweep + selective fp64 -> argmin fp64-exact. Loss fp64,
// fixed order (deterministic).

typedef __attribute__((ext_vector_type(8))) short bf16x8;
typedef __attribute__((ext_vector_type(4))) float f32x4;
typedef __attribute__((ext_vector_type(8))) unsigned short u16x8;

static constexpr int Vn    = 1024;
static constexpr int Hn    = 64;
static constexpr int Nrows = 128 * 512;          // 65536
static constexpr int QSZ   = Nrows * Hn;         // 4194304
#define TAU 0.05f
#define MARGIN 4e-3f

__device__ inline unsigned short f2bf(float f) {         // RNE fp32->bf16
  unsigned u = __float_as_uint(f);
  return (unsigned short)((u + 0x7fffu + ((u >> 16) & 1u)) >> 16);
}
__device__ inline float bf2f(unsigned short h) {
  return __uint_as_float(((unsigned)h) << 16);
}

// ---- ws layout (bytes) ----
// 0      : double cnormd[1024]       (8192)
// 8192   : double partials[1024]     (8192; region reserves 32768)
// 40960  : float  cnormf[1024]       (4096)
// 45056  : int    bestIdx[65536]     (262144)
// 307200 : int    flagCount          (8)
// 307208 : int    flagList[65536]    (262144)
// 573440 : ushort cw[1024*128]       (262144)   [ch(64)|cl(64)] per code

// Codebook prep: thread = (code v, 16-elem segment). Coalesced float4 loads,
// 4-lane shfl_xor fp64 norm reduction, bf16 hi/lo split stores.
__global__ __launch_bounds__(256) void kC(
    const float* __restrict__ cb, unsigned short* __restrict__ cw,
    double* __restrict__ cnd, float* __restrict__ cnf,
    int* __restrict__ flagCount) {
  const int t = blockIdx.x * 256 + threadIdx.x;  // 4096 threads
  if (t == 0) *flagCount = 0;
  const int v = t >> 2, seg = t & 3;
  const float4* src = reinterpret_cast<const float4*>(cb + v * Hn + seg * 16);
  float vals[16];
  double s = 0;
#pragma unroll
  for (int q = 0; q < 4; ++q) {
    float4 f = src[q];
    vals[q * 4 + 0] = f.x; vals[q * 4 + 1] = f.y;
    vals[q * 4 + 2] = f.z; vals[q * 4 + 3] = f.w;
    s += (double)f.x * f.x + (double)f.y * f.y +
         (double)f.z * f.z + (double)f.w * f.w;
  }
  s += __shfl_xor(s, 1);                         // 4-lane group reduce
  s += __shfl_xor(s, 2);
  if (seg == 0) { cnd[v] = s; cnf[v] = (float)s; }
  u16x8 hv, lv0;
  u16x8 hv1, lv1;
#pragma unroll
  for (int j = 0; j < 8; ++j) {
    unsigned short h = f2bf(vals[j]);
    hv[j] = h; lv0[j] = f2bf(vals[j] - bf2f(h));
    unsigned short h2 = f2bf(vals[8 + j]);
    hv1[j] = h2; lv1[j] = f2bf(vals[8 + j] - bf2f(h2));
  }
  u16x8* dh = (u16x8*)(cw + v * 128 + seg * 16);
  dh[0] = hv; dh[1] = hv1;
  u16x8* dl = (u16x8*)(cw + v * 128 + 64 + seg * 16);
  dl[0] = lv0; dl[1] = lv1;
}

// Fused MFMA screen + argmin. Block = 4 waves, 32 rows (2 row-tiles); wave w
// sweeps codes [256w, 256w+256) as 16 code-tiles, fully unrolled with a
// 2-deep register double buffer for B and prologue-prefetched cnf.
// Per tile: K=192 via 6 MFMA ((-2xh).ch + (-2xh).cl + (-2xl).ch), C-init =
// ||c||^2 -> acc = key. C frag: col=lane&15, row=4*(lane>>4)+reg (verified).
__global__ __launch_bounds__(256, 3) void kMF(
    const float* __restrict__ x, const unsigned short* __restrict__ cw,
    const float* __restrict__ cnf, int* __restrict__ bestIdx,
    int* __restrict__ flagCount, int* __restrict__ flagList,
    float* __restrict__ outIdx) {
  __shared__ float sB1[4][32], sB2[4][32];
  __shared__ int   sI[4][32];
  const int tid = threadIdx.x;
  const int lane = tid & 63;
  const int w = tid >> 6;
  const int l15 = lane & 15, g = lane >> 4;
  const int rowBase = blockIdx.x * 32;
  const int codeBase = w * 256;

  // A fragments: 2 row-tiles x {h0,h1,l0,l1} of (-2x).
  bf16x8 A[2][4];
#pragma unroll
  for (int rt = 0; rt < 2; ++rt) {
    const float* xr = x + (long)(rowBase + rt * 16 + l15) * Hn + g * 8;
    float4 fa0 = *(const float4*)(xr + 0);
    float4 fa1 = *(const float4*)(xr + 4);
    float4 fb0 = *(const float4*)(xr + 32);
    float4 fb1 = *(const float4*)(xr + 36);
    float va[8] = {fa0.x, fa0.y, fa0.z, fa0.w, fa1.x, fa1.y, fa1.z, fa1.w};
    float vb[8] = {fb0.x, fb0.y, fb0.z, fb0.w, fb1.x, fb1.y, fb1.z, fb1.w};
    bf16x8 h0, h1, l0, l1;
#pragma unroll
    for (int j = 0; j < 8; ++j) {
      float sa = -2.0f * va[j];
      unsigned short h = f2bf(sa);
      h0[j] = (short)h;
      l0[j] = (short)f2bf(sa - bf2f(h));
      float sb = -2.0f * vb[j];
      unsigned short h2 = f2bf(sb);
      h1[j] = (short)h2;
      l1[j] = (short)f2bf(sb - bf2f(h2));
    }
    A[rt][0] = h0; A[rt][1] = h1; A[rt][2] = l0; A[rt][3] = l1;
  }

  // Prefetch all 16 cnf values (removes per-tile C-init load dependency).
  float cnfv[16];
#pragma unroll
  for (int ct = 0; ct < 16; ++ct) cnfv[ct] = cnf[codeBase + ct * 16 + l15];

  float b1[2][4], b2[2][4];
  int   bi[2][4];
#pragma unroll
  for (int rt = 0; rt < 2; ++rt)
#pragma unroll
    for (int r = 0; r < 4; ++r) { b1[rt][r] = 3.4e38f; b2[rt][r] = 3.4e38f; bi[rt][r] = 0; }

  // B double buffer (static indices via full unroll).
  bf16x8 B[2][4];
  {
    const unsigned short* br = cw + (long)(codeBase + l15) * 128 + g * 8;
    B[0][0] = *(const bf16x8*)(br + 0);
    B[0][1] = *(const bf16x8*)(br + 32);
    B[0][2] = *(const bf16x8*)(br + 64);
    B[0][3] = *(const bf16x8*)(br + 96);
  }

#pragma unroll
  for (int ct = 0; ct < 16; ++ct) {
    const int cur = ct & 1, nxt = cur ^ 1;
    if (ct < 15) {                               // issue next-tile loads early
      const unsigned short* br =
          cw + (long)(codeBase + (ct + 1) * 16 + l15) * 128 + g * 8;
      B[nxt][0] = *(const bf16x8*)(br + 0);
      B[nxt][1] = *(const bf16x8*)(br + 32);
      B[nxt][2] = *(const bf16x8*)(br + 64);
      B[nxt][3] = *(const bf16x8*)(br + 96);
    }
    const int v = codeBase + ct * 16 + l15;
#pragma unroll
    for (int rt = 0; rt < 2; ++rt) {
      f32x4 acc = {cnfv[ct], cnfv[ct], cnfv[ct], cnfv[ct]};  // C-init = ||c||^2
      acc = __builtin_amdgcn_mfma_f32_16x16x32_bf16(A[rt][0], B[cur][0], acc, 0, 0, 0);
      acc = __builtin_amdgcn_mfma_f32_16x16x32_bf16(A[rt][1], B[cur][1], acc, 0, 0, 0);
      acc = __builtin_amdgcn_mfma_f32_16x16x32_bf16(A[rt][0], B[cur][2], acc, 0, 0, 0);
      acc = __builtin_amdgcn_mfma_f32_16x16x32_bf16(A[rt][1], B[cur][3], acc, 0, 0, 0);
      acc = __builtin_amdgcn_mfma_f32_16x16x32_bf16(A[rt][2], B[cur][0], acc, 0, 0, 0);
      acc = __builtin_amdgcn_mfma_f32_16x16x32_bf16(A[rt][3], B[cur][1], acc, 0, 0, 0);
#pragma unroll
      for (int r = 0; r < 4; ++r) {
        float key = acc[r];                      // = ||c||^2 - 2 x.c
        bool lt = key < b1[rt][r];
        b2[rt][r] = __builtin_amdgcn_fmed3f(key, b1[rt][r], b2[rt][r]); // 2nd-best
        b1[rt][r] = fminf(b1[rt][r], key);
        bi[rt][r] = lt ? v : bi[rt][r];
      }
    }
  }

  // Merge top-2 across the 16 lanes holding each row (cols 0..15 subsets).
#pragma unroll
  for (int rt = 0; rt < 2; ++rt)
#pragma unroll
    for (int r = 0; r < 4; ++r) {
      float B1r = b1[rt][r], B2r = b2[rt][r];
      int Ir = bi[rt][r];
#pragma unroll
      for (int m = 1; m < 16; m <<= 1) {
        float o1 = __shfl_xor(B1r, m), o2 = __shfl_xor(B2r, m);
        int oi = __shfl_xor(Ir, m);
        float worse = fmaxf(B1r, o1);
        B2r = fminf(fminf(B2r, o2), worse);
        bool take = (o1 < B1r) || (o1 == B1r && oi < Ir);
        B1r = take ? o1 : B1r;
        Ir  = take ? oi : Ir;
      }
      b1[rt][r] = B1r; b2[rt][r] = B2r; bi[rt][r] = Ir;
    }

  // Writers: lane with l15==r publishes row rt*16 + 4g + r (static reg idx).
#pragma unroll
  for (int rt = 0; rt < 2; ++rt)
#pragma unroll
    for (int r = 0; r < 4; ++r)
      if (l15 == r) {
        int rowIn = rt * 16 + 4 * g + r;
        sB1[w][rowIn] = b1[rt][r];
        sB2[w][rowIn] = b2[rt][r];
        sI[w][rowIn]  = bi[rt][r];
      }
  __syncthreads();

  if (tid < 32) {
    float B1 = sB1[0][tid], B2 = sB2[0][tid];
    int I = sI[0][tid];
#pragma unroll
    for (int ww = 1; ww < 4; ++ww) {
      float o1 = sB1[ww][tid], o2 = sB2[ww][tid];
      int oi = sI[ww][tid];
      float worse = fmaxf(B1, o1);
      B2 = fminf(fminf(B2, o2), worse);
      bool take = (o1 < B1) || (o1 == B1 && oi < I);
      B1 = take ? o1 : B1;
      I  = take ? oi : I;
    }
    const int row = rowBase + tid;
    bestIdx[row] = I;
    outIdx[row] = (float)I;
    if (B2 - B1 <= TAU) {
      int slot = atomicAdd(flagCount, 1);
      flagList[slot] = row;                      // order-independent use
    }
  }
}

// Recheck flagged rows: exact-fp32 sweep of all 1024 codes, then fp64 keys
// only for codes within MARGIN of the fp32 min (|key32-key64| <= ~5e-4).
__global__ __launch_bounds__(256) void k3_recheck(
    const float* __restrict__ x, const float* __restrict__ cb,
    const double* __restrict__ cnd, const float* __restrict__ cnf,
    int* __restrict__ bestIdx,
    const int* __restrict__ flagCount, const int* __restrict__ flagList,
    float* __restrict__ outIdx) {
  __shared__ float xs[64];
  __shared__ float rmin[256];
  __shared__ double dk[256];
  __shared__ int    di[256];
  const int tid = threadIdx.x;
  const int cnt = *flagCount;

  for (int jj = blockIdx.x; jj < cnt; jj += gridDim.x) {
    const int row = flagList[jj];
    if (tid < 16)
      reinterpret_cast<float4*>(xs)[tid] =
          reinterpret_cast<const float4*>(x + (long)row * Hn)[tid];
    __syncthreads();

    float key32[4];
#pragma unroll
    for (int cc = 0; cc < 4; ++cc) {
      const int v = cc * 256 + tid;
      const float4* c4 = reinterpret_cast<const float4*>(cb + v * Hn);
      float d0 = 0, d1 = 0, d2 = 0, d3 = 0;
#pragma unroll
      for (int k = 0; k < 16; ++k) {
        float4 f = c4[k];
        d0 = fmaf(f.x, xs[4 * k + 0], d0);
        d1 = fmaf(f.y, xs[4 * k + 1], d1);
        d2 = fmaf(f.z, xs[4 * k + 2], d2);
        d3 = fmaf(f.w, xs[4 * k + 3], d3);
      }
      key32[cc] = cnf[v] - 2.0f * ((d0 + d1) + (d2 + d3));
    }

    float m = fminf(fminf(key32[0], key32[1]), fminf(key32[2], key32[3]));
    rmin[tid] = m;
    __syncthreads();
    for (int s = 128; s > 0; s >>= 1) {
      if (tid < s) rmin[tid] = fminf(rmin[tid], rmin[tid + s]);
      __syncthreads();
    }
    const float m1 = rmin[0];

    double bk = 1e300;
    int bidx = 0x7FFFFFFF;
#pragma unroll
    for (int cc = 0; cc < 4; ++cc) {
      if (key32[cc] <= m1 + MARGIN) {
        const int v = cc * 256 + tid;
        const float4* c4 = reinterpret_cast<const float4*>(cb + v * Hn);
        double a0 = 0, a1 = 0, a2 = 0, a3 = 0;
#pragma unroll
        for (int k = 0; k < 16; ++k) {
          float4 f = c4[k];
          a0 += (double)f.x * (double)xs[4 * k + 0];
          a1 += (double)f.y * (double)xs[4 * k + 1];
          a2 += (double)f.z * (double)xs[4 * k + 2];
          a3 += (double)f.w * (double)xs[4 * k + 3];
        }
        double key = cnd[v] - 2.0 * ((a0 + a1) + (a2 + a3));
        if (key < bk || (key == bk && v < bidx)) { bk = key; bidx = v; }
      }
    }
    dk[tid] = bk; di[tid] = bidx;
    __syncthreads();
    for (int s = 128; s > 0; s >>= 1) {
      if (tid < s) {
        if (dk[tid + s] < dk[tid] ||
            (dk[tid + s] == dk[tid] && di[tid + s] < di[tid])) {
          dk[tid] = dk[tid + s]; di[tid] = di[tid + s];
        }
      }
      __syncthreads();
    }
    if (tid == 0) {
      bestIdx[row] = di[0];
      outIdx[row] = (float)di[0];
    }
    __syncthreads();
  }
}

// Gather quantized + fp64 loss partials (wave-shuffle reduce, barrier-light).
__global__ __launch_bounds__(256) void k4_gather(
    const float* __restrict__ x, const float* __restrict__ cb,
    const int* __restrict__ bestIdx, float* __restrict__ out,
    double* __restrict__ partials) {
  __shared__ double wsum[4];
  const int tid = threadIdx.x;
  double acc = 0;
#pragma unroll
  for (int q = 0; q < 4; ++q) {
    const int t = blockIdx.x * 1024 + q * 256 + tid;   // float4 index
    const int i = t * 4;
    const int row = i >> 6;
    const int h4 = (i & 63) >> 2;
    const int idx = bestIdx[row];
    float4 qv = reinterpret_cast<const float4*>(cb)[idx * 16 + h4];
    float4 xv = reinterpret_cast<const float4*>(x)[t];
    reinterpret_cast<float4*>(out)[t] = qv;
    double dx = (double)qv.x - (double)xv.x;
    double dy = (double)qv.y - (double)xv.y;
    double dz = (double)qv.z - (double)xv.z;
    double dw = (double)qv.w - (double)xv.w;
    acc += dx * dx + dy * dy + dz * dz + dw * dw;
  }
#pragma unroll
  for (int m = 32; m > 0; m >>= 1) acc += __shfl_down(acc, m);  // fixed order
  if ((tid & 63) == 0) wsum[tid >> 6] = acc;
  __syncthreads();
  if (tid == 0) partials[blockIdx.x] = (wsum[0] + wsum[1]) + (wsum[2] + wsum[3]);
}

__global__ __launch_bounds__(256) void k6_loss(const double* __restrict__ partials,
                                               float* __restrict__ out) {
  __shared__ double red[256];
  double a = 0;
  for (int k = threadIdx.x; k < 1024; k += 256) a += partials[k];  // fixed order
  red[threadIdx.x] = a;
  __syncthreads();
  for (int s = 128; s > 0; s >>= 1) {
    if (threadIdx.x < s) red[threadIdx.x] += red[threadIdx.x + s];
    __syncthreads();
  }
  if (threadIdx.x == 0)
    out[QSZ] = (float)(1.25 * red[0] / (double)QSZ);
}

extern "C" void kernel_launch(void* const* d_in, const int* in_sizes, int n_in,
                              void* d_out, int out_size, void* d_ws, size_t ws_size,
                              hipStream_t stream) {
  const float* x  = (const float*)d_in[0];
  const float* cb = (const float*)d_in[1];
  float* out = (float*)d_out;
  char* ws = (char*)d_ws;

  double* cnd      = (double*)(ws + 0);
  double* partials = (double*)(ws + 8192);
  float*  cnf      = (float*) (ws + 40960);
  int*    bestIdx  = (int*)   (ws + 45056);
  int*    flagCnt  = (int*)   (ws + 307200);
  int*    flagList = (int*)   (ws + 307208);
  unsigned short* cw = (unsigned short*)(ws + 573440);

  float* outIdx = out + QSZ + 1;

  kC        <<<16,   256, 0, stream>>>(cb, cw, cnd, cnf, flagCnt);
  kMF       <<<2048, 256, 0, stream>>>(x, cw, cnf, bestIdx, flagCnt, flagList, outIdx);
  k3_recheck<<<1024, 256, 0, stream>>>(x, cb, cnd, cnf, bestIdx, flagCnt, flagList, outIdx);
  k4_gather <<<1024, 256, 0, stream>>>(x, cb, bestIdx, out, partials);
  k6_loss   <<<1,    256, 0, stream>>>(partials, out);
}